// Round 5
// baseline (183.264 us; speedup 1.0000x reference)
//
#include <hip/hip_runtime.h>
#include <hip/hip_bf16.h>
#include <stdint.h>

#define B_SZ 8192
#define D_SZ 512
#define U_SZ 512
#define M_SZ 16
#define K_SZ 64

typedef short bf16x8 __attribute__((ext_vector_type(8)));
typedef float f32x4 __attribute__((ext_vector_type(4)));

__device__ __forceinline__ unsigned short f2bf(float f) {
  union { float f; unsigned u; } v; v.f = f;
  unsigned r = v.u + 0x7fffu + ((v.u >> 16) & 1u);
  return (unsigned short)(r >> 16);
}

// =====================================================================
// prep1: role-split single launch. ALL outputs are fragment-linear bf16.
//  [0,2048):    kernels [M][D][U] f32 -> kbf [m][ut][kt][j][h][lane][8]
//  [2048,2056): key_kernel [D][K]     -> wkbf [kt][j][h][lane][8]
//  [2056,2568): x [B][D]              -> xbf [bt][kt][i][h][lane][8]
// lane = quad*16+lane16; elem e = k offset kt*64 + h*32 + quad*8 + e.
// ROUND-5: role X rewritten — old version read x with 16 lanes at 2KB
// row stride (32B effective per line). Now: coalesced float4 read ->
// bf16 -> LDS [16][520] -> lane-linear 16B writes to xbf.
// =====================================================================
__global__ __launch_bounds__(256) void prep1(
    const float* __restrict__ x, const float* __restrict__ key_kernel,
    const float* __restrict__ kernels, unsigned short* __restrict__ xbf,
    unsigned short* __restrict__ kbf, unsigned short* __restrict__ wkbf) {
  __shared__ float tf[32][65];
  __shared__ unsigned short sx[16][520];
  int bid = blockIdx.x;
  int t = threadIdx.x;

  if (bid < 2048) {
    // ---- role T: kernels -> kbf (frag-linear B operand) ----
    int m = bid >> 7;
    int rem = bid & 127;
    int a = (rem >> 3) & 15;  // d-tile (32 d's)
    int ut = rem & 7;         // u-tile (64 u's)
    int d0 = a * 32, u0 = ut * 64;
    {
      int dr = t >> 4, uc = t & 15;
      const float* src = kernels + ((size_t)m * D_SZ + d0 + dr) * U_SZ + u0 + uc * 4;
      float4 aa = *(const float4*)src;
      float4 bb = *(const float4*)(src + (size_t)16 * U_SZ);
      tf[dr][uc * 4 + 0] = aa.x; tf[dr][uc * 4 + 1] = aa.y;
      tf[dr][uc * 4 + 2] = aa.z; tf[dr][uc * 4 + 3] = aa.w;
      tf[dr + 16][uc * 4 + 0] = bb.x; tf[dr + 16][uc * 4 + 1] = bb.y;
      tf[dr + 16][uc * 4 + 2] = bb.z; tf[dr + 16][uc * 4 + 3] = bb.w;
    }
    __syncthreads();
    {
      int ur = t >> 2, dc = t & 3;  // u-row 0..63, d-oct 0..3
      int j = ur >> 4, lane16 = ur & 15;
      int kt = a >> 1, h = a & 1;   // quad == dc (d0 multiple of 32)
      unsigned short* dst = kbf +
          (((((size_t)m * 8 + ut) * 8 + kt) * 4 + j) * 2 + h) * 512 +
          ((size_t)dc * 16 + lane16) * 8;
      ushort4 lo, hi;
      lo.x = f2bf(tf[dc * 8 + 0][ur]); lo.y = f2bf(tf[dc * 8 + 1][ur]);
      lo.z = f2bf(tf[dc * 8 + 2][ur]); lo.w = f2bf(tf[dc * 8 + 3][ur]);
      hi.x = f2bf(tf[dc * 8 + 4][ur]); hi.y = f2bf(tf[dc * 8 + 5][ur]);
      hi.z = f2bf(tf[dc * 8 + 6][ur]); hi.w = f2bf(tf[dc * 8 + 7][ur]);
      *(ushort4*)dst = lo;
      *(ushort4*)(dst + 4) = hi;
    }
    return;
  }

  if (bid < 2056) {
    // ---- role W: key_kernel -> wkbf ----
    int kt = bid - 2048;
#pragma unroll
    for (int rep = 0; rep < 2; ++rep) {
      int c = rep * 256 + t;
      int j = c >> 7, h = (c >> 6) & 1, quad = (c >> 4) & 3, ln = c & 15;
      int dd = kt * 64 + h * 32 + quad * 8;
      int u = j * 16 + ln;
      unsigned short v[8];
#pragma unroll
      for (int e = 0; e < 8; ++e)
        v[e] = f2bf(key_kernel[(size_t)(dd + e) * K_SZ + u]);
      unsigned short* dst =
          wkbf + ((size_t)((kt * 4 + j) * 2 + h) * 64 + quad * 16 + ln) * 8;
#pragma unroll
      for (int e = 0; e < 8; ++e) dst[e] = v[e];
    }
    return;
  }

  // ---- role X (v2): x -> xbf via LDS transpose, coalesced reads ----
  {
    int xb0 = bid - 2056;            // 0..511, 16 rows each
    int btx = xb0 >> 3, i = xb0 & 7;
    int b0 = xb0 * 16;
#pragma unroll
    for (int rep = 0; rep < 8; ++rep) {
      int idx = rep * 256 + t;       // 0..2047
      int row = idx >> 7;            // 0..15
      int c4 = (idx & 127) * 4;      // 0..508
      float4 v = *(const float4*)(x + (size_t)(b0 + row) * D_SZ + c4);
      ushort4 o;
      o.x = f2bf(v.x); o.y = f2bf(v.y); o.z = f2bf(v.z); o.w = f2bf(v.w);
      *(ushort4*)(&sx[row][c4]) = o;
    }
    __syncthreads();
    int w = t >> 6, l = t & 63;
    int ln = l & 15, quad = l >> 4;
#pragma unroll
    for (int rep = 0; rep < 4; ++rep) {
      int c = w * 4 + rep;           // chunk 0..15 = (kt,h)
      int kt = c >> 1, h = c & 1;
      const unsigned short* srcp = &sx[ln][kt * 64 + h * 32 + quad * 8];
      ushort4 lo = *(const ushort4*)(srcp);
      ushort4 hi = *(const ushort4*)(srcp + 4);
      unsigned short* dst =
          xbf + ((((size_t)btx * 8 + kt) * 8 + i) * 2 + h) * 512 + (size_t)l * 8;
      *(ushort4*)dst = lo;
      *(ushort4*)(dst + 4) = hi;
    }
  }
}

// =====================================================================
// prep2: keyv = xb @ Wk + bias (MFMA, frags direct from global), then sim.
// 128 blocks x 64 rows. No LDS in GEMM loop; one barrier before sim phase.
// =====================================================================
__global__ __launch_bounds__(256) void prep2(
    const unsigned short* __restrict__ xbf, const unsigned short* __restrict__ wkbf,
    const float* __restrict__ key_bias, const float* __restrict__ keys_map,
    float* __restrict__ simT) {
  __shared__ float kv[64][68];
  __shared__ float sKM[16][64];
  int t = threadIdx.x, w = t >> 6, l = t & 63;
  int blk = blockIdx.x;
  int b0 = blk * 64, bt = blk >> 1, ibase = (blk & 1) * 4;
  int lane16 = l & 15, quad = l >> 4;

  ((float4*)sKM)[t] = ((const float4*)keys_map)[t];

  f32x4 acc[4];
#pragma unroll
  for (int j = 0; j < 4; ++j) acc[j] = (f32x4){0.f, 0.f, 0.f, 0.f};

  for (int kt = 0; kt < 8; ++kt) {
    bf16x8 af[2];
#pragma unroll
    for (int h = 0; h < 2; ++h)
      af[h] = *(const bf16x8*)(xbf +
                               ((((size_t)bt * 8 + kt) * 8 + ibase + w) * 2 + h) * 512 +
                               (size_t)l * 8);
#pragma unroll
    for (int j = 0; j < 4; ++j) {
      bf16x8 b0f = *(const bf16x8*)(wkbf + ((size_t)((kt * 4 + j) * 2 + 0) * 64 + l) * 8);
      bf16x8 b1f = *(const bf16x8*)(wkbf + ((size_t)((kt * 4 + j) * 2 + 1) * 64 + l) * 8);
      acc[j] = __builtin_amdgcn_mfma_f32_16x16x32_bf16(af[0], b0f, acc[j], 0, 0, 0);
      acc[j] = __builtin_amdgcn_mfma_f32_16x16x32_bf16(af[1], b1f, acc[j], 0, 0, 0);
    }
  }
#pragma unroll
  for (int j = 0; j < 4; ++j) {
    float bc = key_bias[j * 16 + lane16];
#pragma unroll
    for (int r = 0; r < 4; ++r)
      kv[w * 16 + quad * 4 + r][j * 16 + lane16] = acc[j][r] + bc;
  }
  __syncthreads();

  int row = t >> 2, mg = (t & 3) * 4;
  float d2[4] = {0.f, 0.f, 0.f, 0.f};
#pragma unroll 8
  for (int k = 0; k < 64; ++k) {
    float kvv = kv[row][k];
#pragma unroll
    for (int q = 0; q < 4; ++q) {
      float df = kvv - sKM[mg + q][k];
      d2[q] += df * df;
    }
  }
#pragma unroll
  for (int q = 0; q < 4; ++q)
    simT[(size_t)(mg + q) * B_SZ + b0 + row] = 1.0f / (sqrtf(d2[q]) + 1.0f);
}

// =====================================================================
// poly_gemm v6: out[b,u] = (1/16) sum_m sim[b,m]*(x@kernels_m + biases_m)
//
// ROUND-5: rounds 0/3/4 all hit the same 21-22 B/cy/CU VMEM request
// ceiling (three different structures, identical 90us, MfmaUtil ~32%).
// Fix = cut request volume ~4x:
//  - 256 blocks (32 bt x 8 ut, ut=bid&7), 256 rows x 64 cols per block.
//  - 4 waves = 4 row-quarters; each wave does ALL 16 modes -> no
//    duplication, no epilogue combine at all.
//  - kbf slices (8KB per (kt,mode)) staged ONCE per block, cooperatively
//    (each wave DMAs 2KB via 2x global_load_lds), 4-buffer rotation,
//    stage s+2 at iter s, ONE raw s_barrier per iter, counted vmcnt
//    (12 when the af-prefetch is in the window, else 4; never 0 in-loop).
//  - af (A-fragments) double-buffered in registers one kt ahead.
//  - sim (16KB) + bias (4KB) staged once; per-CU VMEM = ~1.28 MB
//    (was ~4.8) -> below the 33us MFMA floor.
// Race analysis (4-buf + 1 barrier/iter): stage at iter s targets
// buf[(s+2)&3], last consumed at iter s-2; consume(s-2) precedes
// barrier(s-1) in program order, and the stager has passed barrier(s-1),
// so no wave can still be reading it. vmcnt(N) per wave covers its own
// 2 chunks; barrier(s) after the wait makes all waves' chunks visible.
// =====================================================================
#define STAGE(mode_, kt_, bufi_)                                               \
  {                                                                            \
    const unsigned short* _src = kbf_l +                                       \
        (((size_t)(mode_) * 8 + ut) * 8 + (kt_)) * 4096 + w * 1024;            \
    unsigned short* _dst = Bbuf + (bufi_) * 4096 + w * 1024;                   \
    __builtin_amdgcn_global_load_lds(                                          \
        (const __attribute__((address_space(1))) unsigned int*)(_src),         \
        (__attribute__((address_space(3))) unsigned int*)(_dst), 16, 0, 0);    \
    __builtin_amdgcn_global_load_lds(                                          \
        (const __attribute__((address_space(1))) unsigned int*)(_src + 512),   \
        (__attribute__((address_space(3))) unsigned int*)(_dst + 512), 16, 0,  \
        0);                                                                    \
  }

#define LOAD_AF(dst_, kt_)                                                     \
  _Pragma("unroll") for (int ii = 0; ii < 4; ++ii)                             \
      _Pragma("unroll") for (int h = 0; h < 2; ++h) dst_[ii][h] =              \
      *(const bf16x8*)(xbf +                                                   \
                       ((((size_t)(bt * 2 + (w >> 1)) * 8 + (kt_)) * 8 +       \
                         (w & 1) * 4 + ii) * 2 + h) * 512 +                    \
                       (size_t)l * 8);

__global__ __launch_bounds__(256, 1) void poly_gemm(
    const unsigned short* __restrict__ xbf,  // A frag-linear
    const unsigned short* __restrict__ kbf,  // B frag-linear
    const float* __restrict__ simT,          // [M][B]
    const float* __restrict__ biases,        // [M][U] f32
    float* __restrict__ out) {               // [B][U]
  // LDS: [0,32K) 4x8KB B bufs | [32K,48K) sSim[16][256] | [48K,52K) sBias
  __shared__ __align__(16) char smem[53248];

  int t = threadIdx.x, w = t >> 6, l = t & 63;
  int bid = blockIdx.x;
  int ut = bid & 7, bt = bid >> 3;  // ut: XCD-pinned kbf slice
  int b0 = bt * 256, u0 = ut * 64;
  int lane16 = l & 15, quad = l >> 4;

  unsigned short* Bbuf = (unsigned short*)smem;
  float* sSim = (float*)(smem + 32768);
  float* sBias = (float*)(smem + 49152);

  // ---- stage sim [16][256] and bias [16][64] once ----
  {
    int m = t >> 4, c = t & 15;
    const float* src = simT + (size_t)m * B_SZ + b0 + c * 16;
    float4* dst = (float4*)(sSim + m * 256 + c * 16);
#pragma unroll
    for (int q = 0; q < 4; ++q) dst[q] = ((const float4*)src)[q];
    *(float4*)(sBias + m * 64 + c * 4) =
        *(const float4*)(biases + (size_t)m * U_SZ + u0 + c * 4);
  }

  const unsigned short* kbf_l = kbf + (size_t)l * 8;

  bf16x8 afc[4][2], afn[4][2];

  // prologue: stage s=0,1; load af(kt0); full drain; one block barrier.
  STAGE(0, 0, 0);
  STAGE(1, 0, 1);
  LOAD_AF(afc, 0);
  asm volatile("s_waitcnt vmcnt(0)" ::: "memory");
  __syncthreads();

  f32x4 facc[4][4];
#pragma unroll
  for (int i = 0; i < 4; ++i)
#pragma unroll
    for (int j = 0; j < 4; ++j) facc[i][j] = (f32x4){0.f, 0.f, 0.f, 0.f};

#pragma unroll 1
  for (int kt = 0; kt < 8; ++kt) {
#pragma unroll 1
    for (int mg = 0; mg < 4; ++mg) {
#pragma unroll
      for (int mu = 0; mu < 4; ++mu) {
        const int mode = mg * 4 + mu;
        // stage s+2 (wraps at the tail into already-consumed buffers)
        {
          int mode2 = (mode + 2) & 15;
          int kt2 = (mode >= 14) ? ((kt + 1) & 7) : kt;
          STAGE(mode2, kt2, (mode + 2) & 3);
        }
        if (mode == 0 && kt < 7) { LOAD_AF(afn, kt + 1); }
        // counted waits — never 0 in the main loop
        if (mode <= 1 && kt <= 6)
          asm volatile("s_waitcnt vmcnt(12)" ::: "memory");
        else
          asm volatile("s_waitcnt vmcnt(4)" ::: "memory");
        asm volatile("s_barrier" ::: "memory");

        const unsigned short* lb = Bbuf + (mode & 3) * 4096;
        bf16x8 bfr[4][2];
#pragma unroll
        for (int j = 0; j < 4; ++j)
#pragma unroll
          for (int h = 0; h < 2; ++h)
            bfr[j][h] =
                *(const bf16x8*)(lb + (j * 2 + h) * 512 + (size_t)l * 8);

        f32x4 sv[4];
#pragma unroll
        for (int i = 0; i < 4; ++i)
          sv[i] = *(const f32x4*)(sSim + mode * 256 + w * 64 + i * 16 +
                                  quad * 4);

#pragma unroll
        for (int i = 0; i < 4; ++i)
#pragma unroll
          for (int j = 0; j < 4; ++j) {
            f32x4 p = __builtin_amdgcn_mfma_f32_16x16x32_bf16(
                afc[i][0], bfr[j][0], (f32x4){0.f, 0.f, 0.f, 0.f}, 0, 0, 0);
            p = __builtin_amdgcn_mfma_f32_16x16x32_bf16(afc[i][1], bfr[j][1],
                                                        p, 0, 0, 0);
#pragma unroll
            for (int r = 0; r < 4; ++r) facc[i][j][r] += sv[i][r] * p[r];
          }

        if (kt == 0) {  // sim-weighted bias, once per mode
          float bbv[4];
#pragma unroll
          for (int j = 0; j < 4; ++j)
            bbv[j] = sBias[mode * 64 + j * 16 + lane16];
#pragma unroll
          for (int i = 0; i < 4; ++i)
#pragma unroll
            for (int j = 0; j < 4; ++j)
#pragma unroll
              for (int r = 0; r < 4; ++r)
                facc[i][j][r] += sv[i][r] * bbv[j];
        }
      }
    }
    if (kt < 7) {
#pragma unroll
      for (int ii = 0; ii < 4; ++ii)
#pragma unroll
        for (int h = 0; h < 2; ++h) afc[ii][h] = afn[ii][h];
    }
  }

  // epilogue: drain wrap-stage DMA, direct store (no combine needed)
  asm volatile("s_waitcnt vmcnt(0)" ::: "memory");
#pragma unroll
  for (int i = 0; i < 4; ++i)
#pragma unroll
    for (int r = 0; r < 4; ++r) {
      int row = b0 + w * 64 + i * 16 + quad * 4 + r;
      float* orow = out + (size_t)row * U_SZ + u0;
#pragma unroll
      for (int j = 0; j < 4; ++j)
        orow[j * 16 + lane16] = facc[i][j][r] * 0.0625f;
    }
}

extern "C" void kernel_launch(void* const* d_in, const int* in_sizes, int n_in,
                              void* d_out, int out_size, void* d_ws, size_t ws_size,
                              hipStream_t stream) {
  const float* x = (const float*)d_in[0];
  const float* key_kernel = (const float*)d_in[1];
  const float* key_bias = (const float*)d_in[2];
  const float* keys_map = (const float*)d_in[3];
  const float* kernels = (const float*)d_in[4];
  const float* biases = (const float*)d_in[5];
  float* out = (float*)d_out;

  // ws: xbf 8MB | kbf 8MB | wkbf 64KB | simT 512KB
  char* p = (char*)d_ws;
  unsigned short* xbf = (unsigned short*)p;  p += (size_t)B_SZ * D_SZ * 2;
  unsigned short* kbf = (unsigned short*)p;  p += (size_t)M_SZ * U_SZ * D_SZ * 2;
  unsigned short* wkbf = (unsigned short*)p; p += (size_t)K_SZ * D_SZ * 2;
  float* simT = (float*)p;

  prep1<<<dim3(2568), 256, 0, stream>>>(x, key_kernel, kernels, xbf, kbf, wkbf);
  prep2<<<dim3(128), 256, 0, stream>>>(xbf, wkbf, key_bias, keys_map, simT);
  poly_gemm<<<dim3(256), 256, 0, stream>>>(xbf, kbf, simT, biases, out);
}

// Round 6
// 163.372 us; speedup vs baseline: 1.1218x; 1.1218x over previous
//
#include <hip/hip_runtime.h>
#include <hip/hip_bf16.h>
#include <stdint.h>

#define B_SZ 8192
#define D_SZ 512
#define U_SZ 512
#define M_SZ 16
#define K_SZ 64

typedef short bf16x8 __attribute__((ext_vector_type(8)));
typedef float f32x4 __attribute__((ext_vector_type(4)));

__device__ __forceinline__ unsigned short f2bf(float f) {
  union { float f; unsigned u; } v; v.f = f;
  unsigned r = v.u + 0x7fffu + ((v.u >> 16) & 1u);
  return (unsigned short)(r >> 16);
}

// =====================================================================
// prep1: role-split single launch. ALL outputs are fragment-linear bf16.
//  [0,2048):    kernels [M][D][U] f32 -> kbf [m][ut][kt][j][h][lane][8]
//  [2048,2056): key_kernel [D][K]     -> wkbf [kt][j][h][lane][8]
//  [2056,2568): x [B][D]              -> xbf [bt][kt][i][h][lane][8]
// lane = quad*16+lane16; elem e = k offset kt*64 + h*32 + quad*8 + e.
// =====================================================================
__global__ __launch_bounds__(256) void prep1(
    const float* __restrict__ x, const float* __restrict__ key_kernel,
    const float* __restrict__ kernels, unsigned short* __restrict__ xbf,
    unsigned short* __restrict__ kbf, unsigned short* __restrict__ wkbf) {
  __shared__ float tf[32][65];
  __shared__ unsigned short sx[16][520];
  int bid = blockIdx.x;
  int t = threadIdx.x;

  if (bid < 2048) {
    // ---- role T: kernels -> kbf (frag-linear B operand) ----
    int m = bid >> 7;
    int rem = bid & 127;
    int a = (rem >> 3) & 15;  // d-tile (32 d's)
    int ut = rem & 7;         // u-tile (64 u's)
    int d0 = a * 32, u0 = ut * 64;
    {
      int dr = t >> 4, uc = t & 15;
      const float* src = kernels + ((size_t)m * D_SZ + d0 + dr) * U_SZ + u0 + uc * 4;
      float4 aa = *(const float4*)src;
      float4 bb = *(const float4*)(src + (size_t)16 * U_SZ);
      tf[dr][uc * 4 + 0] = aa.x; tf[dr][uc * 4 + 1] = aa.y;
      tf[dr][uc * 4 + 2] = aa.z; tf[dr][uc * 4 + 3] = aa.w;
      tf[dr + 16][uc * 4 + 0] = bb.x; tf[dr + 16][uc * 4 + 1] = bb.y;
      tf[dr + 16][uc * 4 + 2] = bb.z; tf[dr + 16][uc * 4 + 3] = bb.w;
    }
    __syncthreads();
    {
      int ur = t >> 2, dc = t & 3;  // u-row 0..63, d-oct 0..3
      int j = ur >> 4, lane16 = ur & 15;
      int kt = a >> 1, h = a & 1;   // quad == dc (d0 multiple of 32)
      unsigned short* dst = kbf +
          (((((size_t)m * 8 + ut) * 8 + kt) * 4 + j) * 2 + h) * 512 +
          ((size_t)dc * 16 + lane16) * 8;
      ushort4 lo, hi;
      lo.x = f2bf(tf[dc * 8 + 0][ur]); lo.y = f2bf(tf[dc * 8 + 1][ur]);
      lo.z = f2bf(tf[dc * 8 + 2][ur]); lo.w = f2bf(tf[dc * 8 + 3][ur]);
      hi.x = f2bf(tf[dc * 8 + 4][ur]); hi.y = f2bf(tf[dc * 8 + 5][ur]);
      hi.z = f2bf(tf[dc * 8 + 6][ur]); hi.w = f2bf(tf[dc * 8 + 7][ur]);
      *(ushort4*)dst = lo;
      *(ushort4*)(dst + 4) = hi;
    }
    return;
  }

  if (bid < 2056) {
    // ---- role W: key_kernel -> wkbf ----
    int kt = bid - 2048;
#pragma unroll
    for (int rep = 0; rep < 2; ++rep) {
      int c = rep * 256 + t;
      int j = c >> 7, h = (c >> 6) & 1, quad = (c >> 4) & 3, ln = c & 15;
      int dd = kt * 64 + h * 32 + quad * 8;
      int u = j * 16 + ln;
      unsigned short v[8];
#pragma unroll
      for (int e = 0; e < 8; ++e)
        v[e] = f2bf(key_kernel[(size_t)(dd + e) * K_SZ + u]);
      unsigned short* dst =
          wkbf + ((size_t)((kt * 4 + j) * 2 + h) * 64 + quad * 16 + ln) * 8;
#pragma unroll
      for (int e = 0; e < 8; ++e) dst[e] = v[e];
    }
    return;
  }

  // ---- role X (v2): x -> xbf via LDS transpose, coalesced reads ----
  {
    int xb0 = bid - 2056;            // 0..511, 16 rows each
    int btx = xb0 >> 3, i = xb0 & 7;
    int b0 = xb0 * 16;
#pragma unroll
    for (int rep = 0; rep < 8; ++rep) {
      int idx = rep * 256 + t;       // 0..2047
      int row = idx >> 7;            // 0..15
      int c4 = (idx & 127) * 4;      // 0..508
      float4 v = *(const float4*)(x + (size_t)(b0 + row) * D_SZ + c4);
      ushort4 o;
      o.x = f2bf(v.x); o.y = f2bf(v.y); o.z = f2bf(v.z); o.w = f2bf(v.w);
      *(ushort4*)(&sx[row][c4]) = o;
    }
    __syncthreads();
    int w = t >> 6, l = t & 63;
    int ln = l & 15, quad = l >> 4;
#pragma unroll
    for (int rep = 0; rep < 4; ++rep) {
      int c = w * 4 + rep;           // chunk 0..15 = (kt,h)
      int kt = c >> 1, h = c & 1;
      const unsigned short* srcp = &sx[ln][kt * 64 + h * 32 + quad * 8];
      ushort4 lo = *(const ushort4*)(srcp);
      ushort4 hi = *(const ushort4*)(srcp + 4);
      unsigned short* dst =
          xbf + ((((size_t)btx * 8 + kt) * 8 + i) * 2 + h) * 512 + (size_t)l * 8;
      *(ushort4*)dst = lo;
      *(ushort4*)(dst + 4) = hi;
    }
  }
}

// =====================================================================
// prep2: keyv = xb @ Wk + bias (MFMA, frags direct from global), then sim.
// =====================================================================
__global__ __launch_bounds__(256) void prep2(
    const unsigned short* __restrict__ xbf, const unsigned short* __restrict__ wkbf,
    const float* __restrict__ key_bias, const float* __restrict__ keys_map,
    float* __restrict__ simT) {
  __shared__ float kv[64][68];
  __shared__ float sKM[16][64];
  int t = threadIdx.x, w = t >> 6, l = t & 63;
  int blk = blockIdx.x;
  int b0 = blk * 64, bt = blk >> 1, ibase = (blk & 1) * 4;
  int lane16 = l & 15, quad = l >> 4;

  ((float4*)sKM)[t] = ((const float4*)keys_map)[t];

  f32x4 acc[4];
#pragma unroll
  for (int j = 0; j < 4; ++j) acc[j] = (f32x4){0.f, 0.f, 0.f, 0.f};

  for (int kt = 0; kt < 8; ++kt) {
    bf16x8 af[2];
#pragma unroll
    for (int h = 0; h < 2; ++h)
      af[h] = *(const bf16x8*)(xbf +
                               ((((size_t)bt * 8 + kt) * 8 + ibase + w) * 2 + h) * 512 +
                               (size_t)l * 8);
#pragma unroll
    for (int j = 0; j < 4; ++j) {
      bf16x8 b0f = *(const bf16x8*)(wkbf + ((size_t)((kt * 4 + j) * 2 + 0) * 64 + l) * 8);
      bf16x8 b1f = *(const bf16x8*)(wkbf + ((size_t)((kt * 4 + j) * 2 + 1) * 64 + l) * 8);
      acc[j] = __builtin_amdgcn_mfma_f32_16x16x32_bf16(af[0], b0f, acc[j], 0, 0, 0);
      acc[j] = __builtin_amdgcn_mfma_f32_16x16x32_bf16(af[1], b1f, acc[j], 0, 0, 0);
    }
  }
#pragma unroll
  for (int j = 0; j < 4; ++j) {
    float bc = key_bias[j * 16 + lane16];
#pragma unroll
    for (int r = 0; r < 4; ++r)
      kv[w * 16 + quad * 4 + r][j * 16 + lane16] = acc[j][r] + bc;
  }
  __syncthreads();

  int row = t >> 2, mg = (t & 3) * 4;
  float d2[4] = {0.f, 0.f, 0.f, 0.f};
#pragma unroll 8
  for (int k = 0; k < 64; ++k) {
    float kvv = kv[row][k];
#pragma unroll
    for (int q = 0; q < 4; ++q) {
      float df = kvv - sKM[mg + q][k];
      d2[q] += df * df;
    }
  }
#pragma unroll
  for (int q = 0; q < 4; ++q)
    simT[(size_t)(mg + q) * B_SZ + b0 + row] = 1.0f / (sqrtf(d2[q]) + 1.0f);
}

// =====================================================================
// poly_gemm v7: out[b,u] = (1/16) sum_m sim[b,m]*(x@kernels_m + biases_m)
//
// ROUND-6: R5 proved byte volume wasn't the wall (4x less traffic, 13%
// slower) — the wall is per-iteration latency exposure. This version
// combines R5's minimal-traffic shared staging with 2 waves/SIMD overlap
// and a 4-deep DMA lookahead:
//  - 256 blocks (32 bt x 8 ut XCD-pinned), 256 rows x 64 cols per block.
//  - 512 threads = 8 waves = 8 row-quarters (32 rows each); each wave
//    does ALL 16 modes -> zero duplication, direct store epilogue.
//    2 waves/SIMD overlap each other's stalls within barrier windows.
//  - 8 x 8KB LDS buffers, stage distance 4 (lookahead ~4 iters): stage
//    of slice s+4 issued at iter s; consumed buffer (s+4)&7 was last
//    read at iter s-4, and every wave issuing at s passed barrier(s-1)
//    >= barrier(s-3) > its consume(s-4) -> race-free with margin.
//  - per wave per iter: 1 global_load_lds (1KB), 8 ds_read_b128,
//    16 MFMA, 32 fmac, 1 s_barrier, counted vmcnt (ledger below).
//  - vmcnt ledger (per wave, in-flight oldest->newest at iter s):
//    kt<7,mode 0:  [st(s),st(s+1..3),af4? no: af just issued after
//                   st(s+4)] = [st(s),st(s+1),st(s+2),st(s+3),st(s+4),
//                   af4] (9) -> vmcnt(8) retires st(s).
//    kt<7,mode1-4: 9 in flight, st(s) oldest -> vmcnt(8).
//    kt<7,mode==5: [af4,st(s),st(s+1..4)] -> af older than st(s):
//                   vmcnt(4) (retires af4+st(s)).
//    mode>=6 / kt==7: [st(s),st(s+1..4)] (5) -> vmcnt(4). NOTE kt==7
//                   must NOT use vmcnt(8) (no-op at 5 in flight).
//  - __launch_bounds__(512,2): VGPR cap 256 (R1's squeeze was (512,4)).
// =====================================================================
#define STAGE(mode_, kt_, bufi_)                                               \
  {                                                                            \
    const unsigned short* _src = kbf_l +                                       \
        (((size_t)(mode_) * 8 + ut) * 8 + (kt_)) * 4096 + w * 512;             \
    unsigned short* _dst = Bbuf + (bufi_) * 4096 + w * 512;                    \
    __builtin_amdgcn_global_load_lds(                                          \
        (const __attribute__((address_space(1))) unsigned int*)(_src),         \
        (__attribute__((address_space(3))) unsigned int*)(_dst), 16, 0, 0);    \
  }

#define LOAD_AF(dst_, kt_)                                                     \
  _Pragma("unroll") for (int ii = 0; ii < 2; ++ii)                             \
      _Pragma("unroll") for (int h = 0; h < 2; ++h) {                          \
    int g_ = bt * 16 + w * 2 + ii;                                             \
    dst_[ii][h] = *(const bf16x8*)(                                            \
        xbf + ((((size_t)(g_ >> 3) * 8 + (kt_)) * 8 + (g_ & 7)) * 2 + h) *     \
                  512 +                                                        \
              (size_t)l * 8);                                                  \
  }

__global__ __launch_bounds__(512, 2) void poly_gemm(
    const unsigned short* __restrict__ xbf,  // A frag-linear
    const unsigned short* __restrict__ kbf,  // B frag-linear
    const float* __restrict__ simT,          // [M][B]
    const float* __restrict__ biases,        // [M][U] f32
    float* __restrict__ out) {               // [B][U]
  // LDS: [0,64K) 8x8KB B bufs | [64K,80K) sSim[16][256] | [80K,84K) sBias
  __shared__ __align__(16) char smem[86016];

  int t = threadIdx.x, w = t >> 6, l = t & 63;
  int bid = blockIdx.x;
  int ut = bid & 7, bt = bid >> 3;  // ut: XCD-pinned kbf slice
  int b0 = bt * 256, u0 = ut * 64;
  int lane16 = l & 15, quad = l >> 4;

  unsigned short* Bbuf = (unsigned short*)smem;
  float* sSim = (float*)(smem + 65536);
  float* sBias = (float*)(smem + 81920);

  // ---- stage sim [16][256] and bias [16][64] once (512 threads) ----
  {
    int m = t >> 5, c = (t & 31) * 8;
    const float* src = simT + (size_t)m * B_SZ + b0 + c;
    float4* dst = (float4*)(sSim + m * 256 + c);
    dst[0] = ((const float4*)src)[0];
    dst[1] = ((const float4*)src)[1];
    int bi = t * 2;  // 0..1022
    *(float2*)(sBias + bi) =
        *(const float2*)(biases + (size_t)(bi >> 6) * U_SZ + u0 + (bi & 63));
  }

  const unsigned short* kbf_l = kbf + (size_t)l * 8;

  bf16x8 afc[2][2], afn[2][2];

  // prologue: stage slices s=0..3, load af(kt0), drain, barrier.
  STAGE(0, 0, 0);
  STAGE(1, 0, 1);
  STAGE(2, 0, 2);
  STAGE(3, 0, 3);
  LOAD_AF(afc, 0);
  asm volatile("s_waitcnt vmcnt(0)" ::: "memory");
  __syncthreads();

  f32x4 facc[2][4];
#pragma unroll
  for (int i = 0; i < 2; ++i)
#pragma unroll
    for (int j = 0; j < 4; ++j) facc[i][j] = (f32x4){0.f, 0.f, 0.f, 0.f};

#pragma unroll 1
  for (int kt = 0; kt < 8; ++kt) {
#pragma unroll
    for (int mode = 0; mode < 16; ++mode) {
      const int s = kt * 16 + mode;
      // stage slice s+4
      {
        int mode4 = (mode + 4) & 15;
        int kt4 = (mode >= 12) ? ((kt + 1) & 7) : kt;
        STAGE(mode4, kt4, (s + 4) & 7);
      }
      if (mode == 0 && kt < 7) { LOAD_AF(afn, kt + 1); }
      // counted waits per the ledger (never 0 in-loop)
      if (mode < 5) {
        if (kt < 7)
          asm volatile("s_waitcnt vmcnt(8)" ::: "memory");
        else
          asm volatile("s_waitcnt vmcnt(4)" ::: "memory");
      } else {
        asm volatile("s_waitcnt vmcnt(4)" ::: "memory");
      }
      asm volatile("s_barrier" ::: "memory");

      const unsigned short* lb = Bbuf + (s & 7) * 4096;
      bf16x8 bfr[4][2];
#pragma unroll
      for (int j = 0; j < 4; ++j)
#pragma unroll
        for (int h = 0; h < 2; ++h)
          bfr[j][h] = *(const bf16x8*)(lb + (j * 2 + h) * 512 + (size_t)l * 8);

      f32x4 sv[2];
#pragma unroll
      for (int i = 0; i < 2; ++i)
        sv[i] =
            *(const f32x4*)(sSim + mode * 256 + w * 32 + i * 16 + quad * 4);

#pragma unroll
      for (int i = 0; i < 2; ++i)
#pragma unroll
        for (int j = 0; j < 4; ++j) {
          f32x4 p = __builtin_amdgcn_mfma_f32_16x16x32_bf16(
              afc[i][0], bfr[j][0], (f32x4){0.f, 0.f, 0.f, 0.f}, 0, 0, 0);
          p = __builtin_amdgcn_mfma_f32_16x16x32_bf16(afc[i][1], bfr[j][1], p,
                                                      0, 0, 0);
#pragma unroll
          for (int r = 0; r < 4; ++r) facc[i][j][r] += sv[i][r] * p[r];
        }

      if (kt == 0) {  // sim-weighted bias, once per mode
        float bbv[4];
#pragma unroll
        for (int j = 0; j < 4; ++j)
          bbv[j] = sBias[mode * 64 + j * 16 + lane16];
#pragma unroll
        for (int i = 0; i < 2; ++i)
#pragma unroll
          for (int j = 0; j < 4; ++j)
#pragma unroll
            for (int r = 0; r < 4; ++r) facc[i][j][r] += sv[i][r] * bbv[j];
      }
    }
    if (kt < 7) {
#pragma unroll
      for (int ii = 0; ii < 2; ++ii)
#pragma unroll
        for (int h = 0; h < 2; ++h) afc[ii][h] = afn[ii][h];
    }
  }

  // epilogue: drain wrap-stage DMA, direct store (no combine needed)
  asm volatile("s_waitcnt vmcnt(0)" ::: "memory");
#pragma unroll
  for (int i = 0; i < 2; ++i)
#pragma unroll
    for (int r = 0; r < 4; ++r) {
      int row = b0 + w * 32 + i * 16 + quad * 4 + r;
      float* orow = out + (size_t)row * U_SZ + u0;
#pragma unroll
      for (int j = 0; j < 4; ++j)
        orow[j * 16 + lane16] = facc[i][j][r] * 0.0625f;
    }
}

extern "C" void kernel_launch(void* const* d_in, const int* in_sizes, int n_in,
                              void* d_out, int out_size, void* d_ws, size_t ws_size,
                              hipStream_t stream) {
  const float* x = (const float*)d_in[0];
  const float* key_kernel = (const float*)d_in[1];
  const float* key_bias = (const float*)d_in[2];
  const float* keys_map = (const float*)d_in[3];
  const float* kernels = (const float*)d_in[4];
  const float* biases = (const float*)d_in[5];
  float* out = (float*)d_out;

  // ws: xbf 8MB | kbf 8MB | wkbf 64KB | simT 512KB
  char* p = (char*)d_ws;
  unsigned short* xbf = (unsigned short*)p;  p += (size_t)B_SZ * D_SZ * 2;
  unsigned short* kbf = (unsigned short*)p;  p += (size_t)M_SZ * U_SZ * D_SZ * 2;
  unsigned short* wkbf = (unsigned short*)p; p += (size_t)K_SZ * D_SZ * 2;
  float* simT = (float*)p;

  prep1<<<dim3(2568), 256, 0, stream>>>(x, key_kernel, kernels, xbf, kbf, wkbf);
  prep2<<<dim3(128), 256, 0, stream>>>(xbf, wkbf, key_bias, keys_map, simT);
  poly_gemm<<<dim3(256), 512, 0, stream>>>(xbf, kbf, simT, biases, out);
}